// Round 17
// baseline (712.150 us; speedup 1.0000x reference)
//
#include <hip/hip_runtime.h>

// 3-layer LSTM encoder. B=512, T=512, F=8, HID=128, EMB=64.
// R17 = R16 (4-stage pipeline: L1 | P2 xp-GEMM | L2 | L3, 128 blocks) +
//  (1) weights/bias PRESCALED by exp2 constants (i/f/o: -1.4427, g: -2.8854)
//      at load -> pointwise is exp2(acc) directly (no per-gate muls);
//  (2) O2 layout [t][b][j] -> L2 store / L3 load lanes are line-contiguous;
//  (3) RC=4 ring slots for o1/xp; (4) L1 x-load only on lk==0 lanes.
// ws: [o1 ring 8MB][xp ring 32MB][O2 67MB][flags]

#define DEVI __device__ __forceinline__

typedef _Float16 h4 __attribute__((ext_vector_type(4)));
typedef _Float16 h8 __attribute__((ext_vector_type(8)));
typedef float f4 __attribute__((ext_vector_type(4)));

static constexpr int T_ = 512, TC_ = 16, NC_ = T_ / TC_, RC_ = 4;
static constexpr float KS_ = -1.44269504f;   // i,f,o prescale
static constexpr float KG_ = -2.88539008f;   // g prescale

DEVI float rcpf_(float x) { return __builtin_amdgcn_rcpf(x); }
DEVI float exp2f_(float x) { return __builtin_amdgcn_exp2f(x); }

DEVI h8 cvt8s(const float* p, float s) {
    const float4 a = *reinterpret_cast<const float4*>(p);
    const float4 b = *reinterpret_cast<const float4*>(p + 4);
    return h8{(_Float16)(a.x * s), (_Float16)(a.y * s), (_Float16)(a.z * s), (_Float16)(a.w * s),
              (_Float16)(b.x * s), (_Float16)(b.y * s), (_Float16)(b.z * s), (_Float16)(b.w * s)};
}

DEVI void lds_barrier() {
    asm volatile("s_waitcnt lgkmcnt(0)\n\ts_barrier" ::: "memory");
}
DEVI int ld_flag(int* f) {
    return __hip_atomic_load(f, __ATOMIC_RELAXED, __HIP_MEMORY_SCOPE_AGENT);
}
DEVI void st_flag(int* f, int v) {
    __hip_atomic_store(f, v, __ATOMIC_RELAXED, __HIP_MEMORY_SCOPE_AGENT);
}

// pointwise on PRESCALED accumulators: e = exp2(acc) directly
#define POINTWISE_PROLOG(ACC)                                                   \
    float e0[4], e1[4], e2[4], e3[4];                                           \
    _Pragma("unroll") for (int i = 0; i < 4; i++) {                             \
        e0[i] = exp2f_(ACC[0][i]);                                              \
        e1[i] = exp2f_(ACC[1][i]);                                              \
        e2[i] = exp2f_(ACC[2][i]);                                              \
        e3[i] = exp2f_(ACC[3][i]); }

#define POINTWISE_CELL(i, C, HVAR)                                              \
    const float gi = rcpf_(1.f + e0[i]), gf = rcpf_(1.f + e1[i]);               \
    const float gg = 2.f * rcpf_(1.f + e2[i]) - 1.f, go = rcpf_(1.f + e3[i]);   \
    C[i] = gf * C[i] + gi * gg;                                                 \
    const float HVAR = go * (2.f * rcpf_(1.f + exp2f_(C[i] * KG_)) - 1.f);

DEVI float gscale(int q) { return (q == 2) ? KG_ : KS_; }

// ---------------- stage L1 ----------------
DEVI void stage_L1(int tile, char* smem, const float* x, const float* Wih,
                   const float* Whh, const float* bih, const float* bhh,
                   _Float16* o1, int* c1, int* p1) {
    constexpr int H = 128, KT_H = 4, HP = H + 8;
    const int tid = threadIdx.x, lane = tid & 63, wv = tid >> 6;
    const int lr = lane & 15, lk = lane >> 4;
    const int b0 = tile * 16;
    const int jcol = wv * 16 + lr;
    _Float16 (*h_lds)[16][HP] = (_Float16 (*)[16][HP])smem;

    h8 wbh[4][KT_H], wbx[4];
    float bias[4];
#pragma unroll
    for (int q = 0; q < 4; q++) {
        const float s = gscale(q);
#pragma unroll
        for (int kt = 0; kt < KT_H; kt++)
            wbh[q][kt] = cvt8s(Whh + (size_t)(q * H + jcol) * H + kt * 32 + lk * 8, s);
        wbx[q] = (lk == 0) ? cvt8s(Wih + (size_t)(q * H + jcol) * 8, s) : h8{};
        bias[q] = (bih[q * H + jcol] + bhh[q * H + jcol]) * s;
    }
    float c[4] = {0.f, 0.f, 0.f, 0.f};
    for (int i = tid; i < 2 * 16 * HP; i += 512) ((_Float16*)smem)[i] = (_Float16)0;
    __syncthreads();

    auto load_x = [&](int t, h8& xa) {   // lk!=0 lanes keep zeros
        if (lk == 0) xa = cvt8s(x + ((size_t)(b0 + lr) * T_ + t) * 8, 1.f);
    };
    h8 xa = h8{}, xb = h8{};

#define L1_STEP(TT, CUR, XS) {                                                  \
    const int tt = (TT);                                                        \
    h8 ha[KT_H];                                                                \
    _Pragma("unroll") for (int kt = 0; kt < KT_H; kt++)                         \
        ha[kt] = *reinterpret_cast<const h8*>(&h_lds[CUR][lr][kt * 32 + lk * 8]); \
    f4 acc[4];                                                                  \
    _Pragma("unroll") for (int q = 0; q < 4; q++)                               \
        acc[q] = f4{bias[q], bias[q], bias[q], bias[q]};                        \
    _Pragma("unroll") for (int q = 0; q < 4; q++)                               \
        acc[q] = __builtin_amdgcn_mfma_f32_16x16x32_f16(XS, wbx[q], acc[q], 0, 0, 0); \
    _Pragma("unroll") for (int kt = 0; kt < KT_H; kt++)                         \
        _Pragma("unroll") for (int q = 0; q < 4; q++)                           \
            acc[q] = __builtin_amdgcn_mfma_f32_16x16x32_f16(ha[kt], wbh[q][kt], acc[q], 0, 0, 0); \
    if (tt + 2 < TC_) load_x(t0 + tt + 2, XS);                                  \
    POINTWISE_PROLOG(acc)                                                       \
    _Pragma("unroll") for (int i = 0; i < 4; i++) {                             \
        POINTWISE_CELL(i, c, h)                                                 \
        const int row = lk * 4 + i;                                             \
        h_lds[(CUR) ^ 1][row][jcol] = (_Float16)h;                              \
        o1[(((size_t)(tile * RC_ + slot) * TC_ + tt) * 16 + row) * 128 + jcol] = (_Float16)h; } }

    for (int ch = 0; ch < NC_; ch++) {
        const int slot = ch & (RC_ - 1);
        if (tid == 0) {
            while (ld_flag(c1) < ch - (RC_ - 1)) __builtin_amdgcn_s_sleep(8);
        }
        __syncthreads();
        const int t0 = ch * TC_;
        load_x(t0, xa); load_x(t0 + 1, xb);
        for (int tb = 0; tb < TC_ / 2; tb++) {
            L1_STEP(2 * tb, 0, xa) lds_barrier();
            L1_STEP(2 * tb + 1, 1, xb) lds_barrier();
        }
        asm volatile("s_waitcnt vmcnt(0)" ::: "memory");
        __syncthreads();
        if (tid == 0) { __threadfence(); st_flag(p1, ch + 1); }
    }
#undef L1_STEP
}

// ---------------- stage P2 (xp GEMM; outputs PRESCALED partials) ----------------
DEVI void stage_P2(int tile, const _Float16* o1, _Float16* xp, const float* Wih,
                   const float* bih, const float* bhh,
                   int* p1, int* c1, int* cx, int* px) {
    constexpr int H = 128;
    const int tid = threadIdx.x, lane = tid & 63, wv = tid >> 6;
    const int lr = lane & 15, lk = lane >> 4;
    const int jcol = wv * 16 + lr;

    h8 wbx[4][4];
    float pbias[4];
#pragma unroll
    for (int q = 0; q < 4; q++) {
        const float s = gscale(q);
#pragma unroll
        for (int kt = 0; kt < 4; kt++)
            wbx[q][kt] = cvt8s(Wih + (size_t)(q * H + jcol) * 128 + kt * 32 + lk * 8, s);
        pbias[q] = (bih[q * H + jcol] + bhh[q * H + jcol]) * s;
    }

    for (int ch = 0; ch < NC_; ch++) {
        const int slot = ch & (RC_ - 1);
        if (tid == 0) {
            while (ld_flag(p1) < ch + 1) __builtin_amdgcn_s_sleep(8);
            while (ld_flag(cx) < ch - (RC_ - 1)) __builtin_amdgcn_s_sleep(8);
            __threadfence();
        }
        __syncthreads();
        const size_t ib = (size_t)(tile * RC_ + slot) * TC_ * 2048;
        const size_t ob = (size_t)(tile * RC_ + slot) * TC_ * 8192;
#pragma unroll 4
        for (int t = 0; t < TC_; t++) {
            h8 af[4];
#pragma unroll
            for (int kt = 0; kt < 4; kt++)
                af[kt] = *reinterpret_cast<const h8*>(o1 + ib + (size_t)t * 2048 + lr * 128 + kt * 32 + lk * 8);
            f4 acc[4];
#pragma unroll
            for (int q = 0; q < 4; q++) acc[q] = f4{pbias[q], pbias[q], pbias[q], pbias[q]};
#pragma unroll
            for (int kt = 0; kt < 4; kt++)
#pragma unroll
                for (int q = 0; q < 4; q++)
                    acc[q] = __builtin_amdgcn_mfma_f32_16x16x32_f16(af[kt], wbx[q][kt], acc[q], 0, 0, 0);
#pragma unroll
            for (int q = 0; q < 4; q++) {
                const h4 o = h4{(_Float16)acc[q][0], (_Float16)acc[q][1],
                                (_Float16)acc[q][2], (_Float16)acc[q][3]};
                *reinterpret_cast<h4*>(xp + ob + (size_t)t * 8192 + (wv * 4 + q) * 256 + lane * 4) = o;
            }
        }
        asm volatile("s_waitcnt vmcnt(0)" ::: "memory");
        __syncthreads();
        if (tid == 0) { __threadfence(); st_flag(px, ch + 1); st_flag(c1, ch + 1); }
    }
}

// ---------------- stage L2 ----------------
DEVI void stage_L2(int tile, char* smem, const _Float16* xp, _Float16* O2,
                   const float* Whh, int* px, int* cx, int* p2) {
    constexpr int H = 128, KT_H = 4, HP = H + 8;
    const int tid = threadIdx.x, lane = tid & 63, wv = tid >> 6;
    const int lr = lane & 15, lk = lane >> 4;
    const int b0 = tile * 16;
    const int jcol = wv * 16 + lr;
    _Float16 (*h_lds)[16][HP] = (_Float16 (*)[16][HP])smem;

    h8 wbh[4][KT_H];
#pragma unroll
    for (int q = 0; q < 4; q++) {
        const float s = gscale(q);
#pragma unroll
        for (int kt = 0; kt < KT_H; kt++)
            wbh[q][kt] = cvt8s(Whh + (size_t)(q * H + jcol) * H + kt * 32 + lk * 8, s);
    }
    float c[4] = {0.f, 0.f, 0.f, 0.f};
    for (int i = tid; i < 2 * 16 * HP; i += 512) ((_Float16*)smem)[i] = (_Float16)0;
    __syncthreads();

    h4 xqa[4], xqb[4];

#define LOAD_XP(SLOT, TTL, DST) {                                               \
    const size_t base = ((size_t)(tile * RC_ + (SLOT)) * TC_ + (TTL)) * 8192 + wv * 1024 + lane * 4; \
    _Pragma("unroll") for (int q = 0; q < 4; q++)                               \
        DST[q] = *reinterpret_cast<const h4*>(xp + base + q * 256); }

#define L2_STEP(TT, CUR, XQ) {                                                  \
    const int tt = (TT); const int t = t0 + tt;                                 \
    h8 ha[KT_H];                                                                \
    _Pragma("unroll") for (int kt = 0; kt < KT_H; kt++)                         \
        ha[kt] = *reinterpret_cast<const h8*>(&h_lds[CUR][lr][kt * 32 + lk * 8]); \
    f4 acc[4];                                                                  \
    _Pragma("unroll") for (int q = 0; q < 4; q++)                               \
        acc[q] = f4{(float)XQ[q][0], (float)XQ[q][1], (float)XQ[q][2], (float)XQ[q][3]}; \
    _Pragma("unroll") for (int kt = 0; kt < KT_H; kt++)                         \
        _Pragma("unroll") for (int q = 0; q < 4; q++)                           \
            acc[q] = __builtin_amdgcn_mfma_f32_16x16x32_f16(ha[kt], wbh[q][kt], acc[q], 0, 0, 0); \
    if (tt + 2 < TC_) LOAD_XP(slot, tt + 2, XQ)                                 \
    POINTWISE_PROLOG(acc)                                                       \
    _Pragma("unroll") for (int i = 0; i < 4; i++) {                             \
        POINTWISE_CELL(i, c, h)                                                 \
        const int row = lk * 4 + i;                                             \
        h_lds[(CUR) ^ 1][row][jcol] = (_Float16)h;                              \
        O2[((size_t)t * 512 + (b0 + row)) * 128 + jcol] = (_Float16)h; } }

    for (int ch = 0; ch < NC_; ch++) {
        const int slot = ch & (RC_ - 1);
        if (tid == 0) {
            while (ld_flag(px) < ch + 1) __builtin_amdgcn_s_sleep(8);
            __threadfence();
        }
        __syncthreads();
        const int t0 = ch * TC_;
        LOAD_XP(slot, 0, xqa)
        LOAD_XP(slot, 1, xqb)
        for (int tb = 0; tb < TC_ / 2; tb++) {
            L2_STEP(2 * tb, 0, xqa) lds_barrier();
            L2_STEP(2 * tb + 1, 1, xqb) lds_barrier();
        }
        asm volatile("s_waitcnt vmcnt(0)" ::: "memory");
        __syncthreads();
        if (tid == 0) { __threadfence(); st_flag(p2, ch + 1); st_flag(cx, ch + 1); }
    }
#undef L2_STEP
#undef LOAD_XP
}

// ---------------- stage L3 ----------------
DEVI void stage_L3(int tile, char* smem, const _Float16* O2, const float* Wih,
                   const float* Whh, const float* bih, const float* bhh,
                   float* out, int* p2) {
    constexpr int H = 64, KT_H = 2, KT_X = 4, HP = H + 8;
    const int tid = threadIdx.x, lane = tid & 63, wv = tid >> 6;
    const int lr = lane & 15, lk = lane >> 4;
    const int b0 = tile * 16;
    const bool act = (wv < 4);
    const int jcol = (wv & 3) * 16 + lr;
    _Float16 (*h_lds)[16][HP] = (_Float16 (*)[16][HP])smem;

    h8 wbh[4][KT_H], wbx[4][KT_X];
    float bias[4];
    if (act) {
#pragma unroll
        for (int q = 0; q < 4; q++) {
            const float s = gscale(q);
#pragma unroll
            for (int kt = 0; kt < KT_H; kt++)
                wbh[q][kt] = cvt8s(Whh + (size_t)(q * H + jcol) * H + kt * 32 + lk * 8, s);
#pragma unroll
            for (int kt = 0; kt < KT_X; kt++)
                wbx[q][kt] = cvt8s(Wih + (size_t)(q * H + jcol) * 128 + kt * 32 + lk * 8, s);
            bias[q] = (bih[q * H + jcol] + bhh[q * H + jcol]) * s;
        }
    }
    float c[4] = {0.f, 0.f, 0.f, 0.f};
    for (int i = tid; i < 2 * 16 * HP; i += 512) ((_Float16*)smem)[i] = (_Float16)0;
    __syncthreads();

    auto load_x = [&](int t, h8* xa) {
#pragma unroll
        for (int kt = 0; kt < KT_X; kt++)
            xa[kt] = *reinterpret_cast<const h8*>(
                O2 + ((size_t)t * 512 + (b0 + lr)) * 128 + kt * 32 + lk * 8);
    };
    h8 xa[KT_X], xb[KT_X];

#define L3_STEP(TT, CUR, XS) {                                                  \
    const int tt = (TT); const int t = t0 + tt;                                 \
    if (act) {                                                                  \
        h8 ha[KT_H];                                                            \
        _Pragma("unroll") for (int kt = 0; kt < KT_H; kt++)                     \
            ha[kt] = *reinterpret_cast<const h8*>(&h_lds[CUR][lr][kt * 32 + lk * 8]); \
        f4 acc[4];                                                              \
        _Pragma("unroll") for (int q = 0; q < 4; q++)                           \
            acc[q] = f4{bias[q], bias[q], bias[q], bias[q]};                    \
        _Pragma("unroll") for (int kt = 0; kt < KT_X; kt++)                     \
            _Pragma("unroll") for (int q = 0; q < 4; q++)                       \
                acc[q] = __builtin_amdgcn_mfma_f32_16x16x32_f16(XS[kt], wbx[q][kt], acc[q], 0, 0, 0); \
        _Pragma("unroll") for (int kt = 0; kt < KT_H; kt++)                     \
            _Pragma("unroll") for (int q = 0; q < 4; q++)                       \
                acc[q] = __builtin_amdgcn_mfma_f32_16x16x32_f16(ha[kt], wbh[q][kt], acc[q], 0, 0, 0); \
        if (tt + 2 < TC_) load_x(t + 2, XS);                                    \
        POINTWISE_PROLOG(acc)                                                   \
        _Pragma("unroll") for (int i = 0; i < 4; i++) {                         \
            POINTWISE_CELL(i, c, h)                                             \
            const int row = lk * 4 + i;                                         \
            h_lds[(CUR) ^ 1][row][jcol] = (_Float16)h;                          \
            if (t == T_ - 1) out[(size_t)(b0 + row) * 64 + jcol] = h; } } }

    for (int ch = 0; ch < NC_; ch++) {
        if (tid == 0) {
            while (ld_flag(p2) < ch + 1) __builtin_amdgcn_s_sleep(8);
            __threadfence();
        }
        __syncthreads();
        const int t0 = ch * TC_;
        if (act) { load_x(t0, xa); load_x(t0 + 1, xb); }
        for (int tb = 0; tb < TC_ / 2; tb++) {
            L3_STEP(2 * tb, 0, xa) lds_barrier();
            L3_STEP(2 * tb + 1, 1, xb) lds_barrier();
        }
    }
#undef L3_STEP
}

__global__ __launch_bounds__(512, 1)
void mega_k(const float* __restrict__ x,
            const float* __restrict__ Wih1, const float* __restrict__ Whh1,
            const float* __restrict__ bih1, const float* __restrict__ bhh1,
            const float* __restrict__ Wih2, const float* __restrict__ Whh2,
            const float* __restrict__ bih2, const float* __restrict__ bhh2,
            const float* __restrict__ Wih3, const float* __restrict__ Whh3,
            const float* __restrict__ bih3, const float* __restrict__ bhh3,
            _Float16* __restrict__ o1ring, _Float16* __restrict__ xpring,
            _Float16* __restrict__ O2, float* __restrict__ out,
            int* __restrict__ flags) {
    extern __shared__ char smem[];
    const int bid = blockIdx.x;
    int* p1 = flags;          // L1 chunk done     [32]
    int* c1 = flags + 32;     // P2 consumed O1    [32]
    int* px = flags + 64;     // P2 xp slot done   [32]
    int* cx = flags + 96;     // L2 consumed xp    [32]
    int* p2 = flags + 128;    // L2 chunk done     [32]
    if (bid < 32) {
        stage_L1(bid, smem, x, Wih1, Whh1, bih1, bhh1, o1ring, c1 + bid, p1 + bid);
    } else if (bid < 64) {
        const int t = bid - 32;
        stage_P2(t, o1ring, xpring, Wih2, bih2, bhh2, p1 + t, c1 + t, cx + t, px + t);
    } else if (bid < 96) {
        const int t = bid - 64;
        stage_L2(t, smem, xpring, O2, Whh2, px + t, cx + t, p2 + t);
    } else {
        const int t = bid - 96;
        stage_L3(t, smem, O2, Wih3, Whh3, bih3, bhh3, out, p2 + t);
    }
}

__global__ void zero_flags_k(int* flags) {
    if (threadIdx.x < 160)
        __hip_atomic_store(flags + threadIdx.x, 0, __ATOMIC_RELAXED,
                           __HIP_MEMORY_SCOPE_AGENT);
}

extern "C" void kernel_launch(void* const* d_in, const int* in_sizes, int n_in,
                              void* d_out, int out_size, void* d_ws, size_t ws_size,
                              hipStream_t stream) {
    const float* x = (const float*)d_in[0];
    float* out = (float*)d_out;

    char* ws = (char*)d_ws;
    _Float16* o1ring = (_Float16*)ws;                          // 8,388,608 B
    _Float16* xpring = (_Float16*)(ws + (size_t)8388608);      // 33,554,432 B
    _Float16* O2     = (_Float16*)(ws + (size_t)41943040);     // 67,108,864 B
    int* flags       = (int*)(ws + (size_t)109051904);         // 640 B
    (void)ws_size; (void)in_sizes; (void)n_in; (void)out_size;

    zero_flags_k<<<1, 192, 0, stream>>>(flags);
    mega_k<<<128, 512, 8704, stream>>>(
        x,
        (const float*)d_in[1], (const float*)d_in[2], (const float*)d_in[3], (const float*)d_in[4],
        (const float*)d_in[5], (const float*)d_in[6], (const float*)d_in[7], (const float*)d_in[8],
        (const float*)d_in[9], (const float*)d_in[10], (const float*)d_in[11], (const float*)d_in[12],
        o1ring, xpring, O2, out, flags);
}

// Round 18
// 703.946 us; speedup vs baseline: 1.0117x; 1.0117x over previous
//
#include <hip/hip_runtime.h>

// 3-layer LSTM encoder. B=512, T=512, F=8, HID=128, EMB=64.
// R18 = R16 4-stage pipeline (L1 | P2 xp-GEMM | L2 | L3, 128 blocks) +
//  split accumulators: each gate acc is TWO independent halves (accL: kt 0-1,
//  accH: kt 2-3) -> dependent-MFMA chain depth 4 -> 2, merged by one add.
//  Keeps R17 prescale (exp2 consts folded into weights/bias) and RC=4 rings;
//  O2 back to [b][t][j] (R16's better-FETCH layout).
// ws: [o1 ring 8MB][xp ring 32MB][O2 67MB][flags]

#define DEVI __device__ __forceinline__

typedef _Float16 h4 __attribute__((ext_vector_type(4)));
typedef _Float16 h8 __attribute__((ext_vector_type(8)));
typedef float f4 __attribute__((ext_vector_type(4)));

static constexpr int T_ = 512, TC_ = 16, NC_ = T_ / TC_, RC_ = 4;
static constexpr float KS_ = -1.44269504f;   // i,f,o prescale
static constexpr float KG_ = -2.88539008f;   // g prescale

DEVI float rcpf_(float x) { return __builtin_amdgcn_rcpf(x); }
DEVI float exp2f_(float x) { return __builtin_amdgcn_exp2f(x); }

DEVI h8 cvt8s(const float* p, float s) {
    const float4 a = *reinterpret_cast<const float4*>(p);
    const float4 b = *reinterpret_cast<const float4*>(p + 4);
    return h8{(_Float16)(a.x * s), (_Float16)(a.y * s), (_Float16)(a.z * s), (_Float16)(a.w * s),
              (_Float16)(b.x * s), (_Float16)(b.y * s), (_Float16)(b.z * s), (_Float16)(b.w * s)};
}

DEVI void lds_barrier() {
    asm volatile("s_waitcnt lgkmcnt(0)\n\ts_barrier" ::: "memory");
}
DEVI int ld_flag(int* f) {
    return __hip_atomic_load(f, __ATOMIC_RELAXED, __HIP_MEMORY_SCOPE_AGENT);
}
DEVI void st_flag(int* f, int v) {
    __hip_atomic_store(f, v, __ATOMIC_RELAXED, __HIP_MEMORY_SCOPE_AGENT);
}

// pointwise on PRESCALED merged accumulators
#define POINTWISE_PROLOG(AL, AH)                                                \
    float e0[4], e1[4], e2[4], e3[4];                                           \
    _Pragma("unroll") for (int i = 0; i < 4; i++) {                             \
        e0[i] = exp2f_(AL[0][i] + AH[0][i]);                                    \
        e1[i] = exp2f_(AL[1][i] + AH[1][i]);                                    \
        e2[i] = exp2f_(AL[2][i] + AH[2][i]);                                    \
        e3[i] = exp2f_(AL[3][i] + AH[3][i]); }

#define POINTWISE_CELL(i, C, HVAR)                                              \
    const float gi = rcpf_(1.f + e0[i]), gf = rcpf_(1.f + e1[i]);               \
    const float gg = 2.f * rcpf_(1.f + e2[i]) - 1.f, go = rcpf_(1.f + e3[i]);   \
    C[i] = gf * C[i] + gi * gg;                                                 \
    const float HVAR = go * (2.f * rcpf_(1.f + exp2f_(C[i] * KG_)) - 1.f);

DEVI float gscale(int q) { return (q == 2) ? KG_ : KS_; }

// ---------------- stage L1 ----------------
DEVI void stage_L1(int tile, char* smem, const float* x, const float* Wih,
                   const float* Whh, const float* bih, const float* bhh,
                   _Float16* o1, int* c1, int* p1) {
    constexpr int H = 128, KT_H = 4, HP = H + 8;
    const int tid = threadIdx.x, lane = tid & 63, wv = tid >> 6;
    const int lr = lane & 15, lk = lane >> 4;
    const int b0 = tile * 16;
    const int jcol = wv * 16 + lr;
    _Float16 (*h_lds)[16][HP] = (_Float16 (*)[16][HP])smem;

    h8 wbh[4][KT_H], wbx[4];
    float bias[4];
#pragma unroll
    for (int q = 0; q < 4; q++) {
        const float s = gscale(q);
#pragma unroll
        for (int kt = 0; kt < KT_H; kt++)
            wbh[q][kt] = cvt8s(Whh + (size_t)(q * H + jcol) * H + kt * 32 + lk * 8, s);
        wbx[q] = (lk == 0) ? cvt8s(Wih + (size_t)(q * H + jcol) * 8, s) : h8{};
        bias[q] = (bih[q * H + jcol] + bhh[q * H + jcol]) * s;
    }
    float c[4] = {0.f, 0.f, 0.f, 0.f};
    for (int i = tid; i < 2 * 16 * HP; i += 512) ((_Float16*)smem)[i] = (_Float16)0;
    __syncthreads();

    auto load_x = [&](int t, h8& xa) {
        if (lk == 0) xa = cvt8s(x + ((size_t)(b0 + lr) * T_ + t) * 8, 1.f);
    };
    h8 xa = h8{}, xb = h8{};

    // accL: x-MFMA + h kt 0,1 (2-deep after seed); accH: bias + h kt 2,3 (2-deep)
#define L1_STEP(TT, CUR, XS) {                                                  \
    const int tt = (TT);                                                        \
    h8 ha[KT_H];                                                                \
    _Pragma("unroll") for (int kt = 0; kt < KT_H; kt++)                         \
        ha[kt] = *reinterpret_cast<const h8*>(&h_lds[CUR][lr][kt * 32 + lk * 8]); \
    f4 aL[4], aH[4];                                                            \
    _Pragma("unroll") for (int q = 0; q < 4; q++) {                             \
        aL[q] = f4{0.f, 0.f, 0.f, 0.f};                                         \
        aH[q] = f4{bias[q], bias[q], bias[q], bias[q]}; }                       \
    _Pragma("unroll") for (int q = 0; q < 4; q++)                               \
        aL[q] = __builtin_amdgcn_mfma_f32_16x16x32_f16(XS, wbx[q], aL[q], 0, 0, 0); \
    _Pragma("unroll") for (int q = 0; q < 4; q++) {                             \
        aL[q] = __builtin_amdgcn_mfma_f32_16x16x32_f16(ha[0], wbh[q][0], aL[q], 0, 0, 0); \
        aH[q] = __builtin_amdgcn_mfma_f32_16x16x32_f16(ha[2], wbh[q][2], aH[q], 0, 0, 0); } \
    _Pragma("unroll") for (int q = 0; q < 4; q++) {                             \
        aL[q] = __builtin_amdgcn_mfma_f32_16x16x32_f16(ha[1], wbh[q][1], aL[q], 0, 0, 0); \
        aH[q] = __builtin_amdgcn_mfma_f32_16x16x32_f16(ha[3], wbh[q][3], aH[q], 0, 0, 0); } \
    if (tt + 2 < TC_) load_x(t0 + tt + 2, XS);                                  \
    POINTWISE_PROLOG(aL, aH)                                                    \
    _Pragma("unroll") for (int i = 0; i < 4; i++) {                             \
        POINTWISE_CELL(i, c, h)                                                 \
        const int row = lk * 4 + i;                                             \
        h_lds[(CUR) ^ 1][row][jcol] = (_Float16)h;                              \
        o1[(((size_t)(tile * RC_ + slot) * TC_ + tt) * 16 + row) * 128 + jcol] = (_Float16)h; } }

    for (int ch = 0; ch < NC_; ch++) {
        const int slot = ch & (RC_ - 1);
        if (tid == 0) {
            while (ld_flag(c1) < ch - (RC_ - 1)) __builtin_amdgcn_s_sleep(8);
        }
        __syncthreads();
        const int t0 = ch * TC_;
        load_x(t0, xa); load_x(t0 + 1, xb);
        for (int tb = 0; tb < TC_ / 2; tb++) {
            L1_STEP(2 * tb, 0, xa) lds_barrier();
            L1_STEP(2 * tb + 1, 1, xb) lds_barrier();
        }
        asm volatile("s_waitcnt vmcnt(0)" ::: "memory");
        __syncthreads();
        if (tid == 0) { __threadfence(); st_flag(p1, ch + 1); }
    }
#undef L1_STEP
}

// ---------------- stage P2 (xp GEMM; PRESCALED output) ----------------
DEVI void stage_P2(int tile, const _Float16* o1, _Float16* xp, const float* Wih,
                   const float* bih, const float* bhh,
                   int* p1, int* c1, int* cx, int* px) {
    constexpr int H = 128;
    const int tid = threadIdx.x, lane = tid & 63, wv = tid >> 6;
    const int lr = lane & 15, lk = lane >> 4;
    const int jcol = wv * 16 + lr;

    h8 wbx[4][4];
    float pbias[4];
#pragma unroll
    for (int q = 0; q < 4; q++) {
        const float s = gscale(q);
#pragma unroll
        for (int kt = 0; kt < 4; kt++)
            wbx[q][kt] = cvt8s(Wih + (size_t)(q * H + jcol) * 128 + kt * 32 + lk * 8, s);
        pbias[q] = (bih[q * H + jcol] + bhh[q * H + jcol]) * s;
    }

    for (int ch = 0; ch < NC_; ch++) {
        const int slot = ch & (RC_ - 1);
        if (tid == 0) {
            while (ld_flag(p1) < ch + 1) __builtin_amdgcn_s_sleep(8);
            while (ld_flag(cx) < ch - (RC_ - 1)) __builtin_amdgcn_s_sleep(8);
            __threadfence();
        }
        __syncthreads();
        const size_t ib = (size_t)(tile * RC_ + slot) * TC_ * 2048;
        const size_t ob = (size_t)(tile * RC_ + slot) * TC_ * 8192;
#pragma unroll 4
        for (int t = 0; t < TC_; t++) {
            h8 af[4];
#pragma unroll
            for (int kt = 0; kt < 4; kt++)
                af[kt] = *reinterpret_cast<const h8*>(o1 + ib + (size_t)t * 2048 + lr * 128 + kt * 32 + lk * 8);
            f4 acc[4];
#pragma unroll
            for (int q = 0; q < 4; q++) acc[q] = f4{pbias[q], pbias[q], pbias[q], pbias[q]};
#pragma unroll
            for (int kt = 0; kt < 4; kt++)
#pragma unroll
                for (int q = 0; q < 4; q++)
                    acc[q] = __builtin_amdgcn_mfma_f32_16x16x32_f16(af[kt], wbx[q][kt], acc[q], 0, 0, 0);
#pragma unroll
            for (int q = 0; q < 4; q++) {
                const h4 o = h4{(_Float16)acc[q][0], (_Float16)acc[q][1],
                                (_Float16)acc[q][2], (_Float16)acc[q][3]};
                *reinterpret_cast<h4*>(xp + ob + (size_t)t * 8192 + (wv * 4 + q) * 256 + lane * 4) = o;
            }
        }
        asm volatile("s_waitcnt vmcnt(0)" ::: "memory");
        __syncthreads();
        if (tid == 0) { __threadfence(); st_flag(px, ch + 1); st_flag(c1, ch + 1); }
    }
}

// ---------------- stage L2 ----------------
DEVI void stage_L2(int tile, char* smem, const _Float16* xp, _Float16* O2,
                   const float* Whh, int* px, int* cx, int* p2) {
    constexpr int H = 128, KT_H = 4, HP = H + 8;
    const int tid = threadIdx.x, lane = tid & 63, wv = tid >> 6;
    const int lr = lane & 15, lk = lane >> 4;
    const int b0 = tile * 16;
    const int jcol = wv * 16 + lr;
    _Float16 (*h_lds)[16][HP] = (_Float16 (*)[16][HP])smem;

    h8 wbh[4][KT_H];
#pragma unroll
    for (int q = 0; q < 4; q++) {
        const float s = gscale(q);
#pragma unroll
        for (int kt = 0; kt < KT_H; kt++)
            wbh[q][kt] = cvt8s(Whh + (size_t)(q * H + jcol) * H + kt * 32 + lk * 8, s);
    }
    float c[4] = {0.f, 0.f, 0.f, 0.f};
    for (int i = tid; i < 2 * 16 * HP; i += 512) ((_Float16*)smem)[i] = (_Float16)0;
    __syncthreads();

    h4 xqa[4], xqb[4];

#define LOAD_XP(SLOT, TTL, DST) {                                               \
    const size_t base = ((size_t)(tile * RC_ + (SLOT)) * TC_ + (TTL)) * 8192 + wv * 1024 + lane * 4; \
    _Pragma("unroll") for (int q = 0; q < 4; q++)                               \
        DST[q] = *reinterpret_cast<const h4*>(xp + base + q * 256); }

    // accL: xp seed + h kt 0,1 ; accH: 0 + h kt 2,3 (both 2-deep)
#define L2_STEP(TT, CUR, XQ) {                                                  \
    const int tt = (TT); const int t = t0 + tt;                                 \
    h8 ha[KT_H];                                                                \
    _Pragma("unroll") for (int kt = 0; kt < KT_H; kt++)                         \
        ha[kt] = *reinterpret_cast<const h8*>(&h_lds[CUR][lr][kt * 32 + lk * 8]); \
    f4 aL[4], aH[4];                                                            \
    _Pragma("unroll") for (int q = 0; q < 4; q++) {                             \
        aL[q] = f4{(float)XQ[q][0], (float)XQ[q][1], (float)XQ[q][2], (float)XQ[q][3]}; \
        aH[q] = f4{0.f, 0.f, 0.f, 0.f}; }                                       \
    _Pragma("unroll") for (int q = 0; q < 4; q++) {                             \
        aL[q] = __builtin_amdgcn_mfma_f32_16x16x32_f16(ha[0], wbh[q][0], aL[q], 0, 0, 0); \
        aH[q] = __builtin_amdgcn_mfma_f32_16x16x32_f16(ha[2], wbh[q][2], aH[q], 0, 0, 0); } \
    _Pragma("unroll") for (int q = 0; q < 4; q++) {                             \
        aL[q] = __builtin_amdgcn_mfma_f32_16x16x32_f16(ha[1], wbh[q][1], aL[q], 0, 0, 0); \
        aH[q] = __builtin_amdgcn_mfma_f32_16x16x32_f16(ha[3], wbh[q][3], aH[q], 0, 0, 0); } \
    if (tt + 2 < TC_) LOAD_XP(slot, tt + 2, XQ)                                 \
    POINTWISE_PROLOG(aL, aH)                                                    \
    _Pragma("unroll") for (int i = 0; i < 4; i++) {                             \
        POINTWISE_CELL(i, c, h)                                                 \
        const int row = lk * 4 + i;                                             \
        h_lds[(CUR) ^ 1][row][jcol] = (_Float16)h;                              \
        O2[((size_t)(b0 + row) * T_ + t) * 128 + jcol] = (_Float16)h; } }

    for (int ch = 0; ch < NC_; ch++) {
        const int slot = ch & (RC_ - 1);
        if (tid == 0) {
            while (ld_flag(px) < ch + 1) __builtin_amdgcn_s_sleep(8);
            __threadfence();
        }
        __syncthreads();
        const int t0 = ch * TC_;
        LOAD_XP(slot, 0, xqa)
        LOAD_XP(slot, 1, xqb)
        for (int tb = 0; tb < TC_ / 2; tb++) {
            L2_STEP(2 * tb, 0, xqa) lds_barrier();
            L2_STEP(2 * tb + 1, 1, xqb) lds_barrier();
        }
        asm volatile("s_waitcnt vmcnt(0)" ::: "memory");
        __syncthreads();
        if (tid == 0) { __threadfence(); st_flag(p2, ch + 1); st_flag(cx, ch + 1); }
    }
#undef L2_STEP
#undef LOAD_XP
}

// ---------------- stage L3 ----------------
DEVI void stage_L3(int tile, char* smem, const _Float16* O2, const float* Wih,
                   const float* Whh, const float* bih, const float* bhh,
                   float* out, int* p2) {
    constexpr int H = 64, KT_H = 2, KT_X = 4, HP = H + 8;
    const int tid = threadIdx.x, lane = tid & 63, wv = tid >> 6;
    const int lr = lane & 15, lk = lane >> 4;
    const int b0 = tile * 16;
    const bool act = (wv < 4);
    const int jcol = (wv & 3) * 16 + lr;
    _Float16 (*h_lds)[16][HP] = (_Float16 (*)[16][HP])smem;

    h8 wbh[4][KT_H], wbx[4][KT_X];
    float bias[4];
    if (act) {
#pragma unroll
        for (int q = 0; q < 4; q++) {
            const float s = gscale(q);
#pragma unroll
            for (int kt = 0; kt < KT_H; kt++)
                wbh[q][kt] = cvt8s(Whh + (size_t)(q * H + jcol) * H + kt * 32 + lk * 8, s);
#pragma unroll
            for (int kt = 0; kt < KT_X; kt++)
                wbx[q][kt] = cvt8s(Wih + (size_t)(q * H + jcol) * 128 + kt * 32 + lk * 8, s);
            bias[q] = (bih[q * H + jcol] + bhh[q * H + jcol]) * s;
        }
    }
    float c[4] = {0.f, 0.f, 0.f, 0.f};
    for (int i = tid; i < 2 * 16 * HP; i += 512) ((_Float16*)smem)[i] = (_Float16)0;
    __syncthreads();

    auto load_x = [&](int t, h8* xa) {
#pragma unroll
        for (int kt = 0; kt < KT_X; kt++)
            xa[kt] = *reinterpret_cast<const h8*>(
                O2 + ((size_t)(b0 + lr) * T_ + t) * 128 + kt * 32 + lk * 8);
    };
    h8 xa[KT_X], xb[KT_X];

    // aL: x kt0,1 + h kt0 ; aH: bias + x kt2,3 + h kt1 (both 3-deep vs 6)
#define L3_STEP(TT, CUR, XS) {                                                  \
    const int tt = (TT); const int t = t0 + tt;                                 \
    if (act) {                                                                  \
        h8 ha[KT_H];                                                            \
        _Pragma("unroll") for (int kt = 0; kt < KT_H; kt++)                     \
            ha[kt] = *reinterpret_cast<const h8*>(&h_lds[CUR][lr][kt * 32 + lk * 8]); \
        f4 aL[4], aH[4];                                                        \
        _Pragma("unroll") for (int q = 0; q < 4; q++) {                         \
            aL[q] = f4{0.f, 0.f, 0.f, 0.f};                                     \
            aH[q] = f4{bias[q], bias[q], bias[q], bias[q]}; }                   \
        _Pragma("unroll") for (int q = 0; q < 4; q++) {                         \
            aL[q] = __builtin_amdgcn_mfma_f32_16x16x32_f16(XS[0], wbx[q][0], aL[q], 0, 0, 0); \
            aH[q] = __builtin_amdgcn_mfma_f32_16x16x32_f16(XS[2], wbx[q][2], aH[q], 0, 0, 0); } \
        _Pragma("unroll") for (int q = 0; q < 4; q++) {                         \
            aL[q] = __builtin_amdgcn_mfma_f32_16x16x32_f16(XS[1], wbx[q][1], aL[q], 0, 0, 0); \
            aH[q] = __builtin_amdgcn_mfma_f32_16x16x32_f16(XS[3], wbx[q][3], aH[q], 0, 0, 0); } \
        _Pragma("unroll") for (int q = 0; q < 4; q++) {                         \
            aL[q] = __builtin_amdgcn_mfma_f32_16x16x32_f16(ha[0], wbh[q][0], aL[q], 0, 0, 0); \
            aH[q] = __builtin_amdgcn_mfma_f32_16x16x32_f16(ha[1], wbh[q][1], aH[q], 0, 0, 0); } \
        if (tt + 2 < TC_) load_x(t + 2, XS);                                    \
        POINTWISE_PROLOG(aL, aH)                                                \
        _Pragma("unroll") for (int i = 0; i < 4; i++) {                         \
            POINTWISE_CELL(i, c, h)                                             \
            const int row = lk * 4 + i;                                         \
            h_lds[(CUR) ^ 1][row][jcol] = (_Float16)h;                          \
            if (t == T_ - 1) out[(size_t)(b0 + row) * 64 + jcol] = h; } } }

    for (int ch = 0; ch < NC_; ch++) {
        if (tid == 0) {
            while (ld_flag(p2) < ch + 1) __builtin_amdgcn_s_sleep(8);
            __threadfence();
        }
        __syncthreads();
        const int t0 = ch * TC_;
        if (act) { load_x(t0, xa); load_x(t0 + 1, xb); }
        for (int tb = 0; tb < TC_ / 2; tb++) {
            L3_STEP(2 * tb, 0, xa) lds_barrier();
            L3_STEP(2 * tb + 1, 1, xb) lds_barrier();
        }
    }
#undef L3_STEP
}

__global__ __launch_bounds__(512, 1)
void mega_k(const float* __restrict__ x,
            const float* __restrict__ Wih1, const float* __restrict__ Whh1,
            const float* __restrict__ bih1, const float* __restrict__ bhh1,
            const float* __restrict__ Wih2, const float* __restrict__ Whh2,
            const float* __restrict__ bih2, const float* __restrict__ bhh2,
            const float* __restrict__ Wih3, const float* __restrict__ Whh3,
            const float* __restrict__ bih3, const float* __restrict__ bhh3,
            _Float16* __restrict__ o1ring, _Float16* __restrict__ xpring,
            _Float16* __restrict__ O2, float* __restrict__ out,
            int* __restrict__ flags) {
    extern __shared__ char smem[];
    const int bid = blockIdx.x;
    int* p1 = flags;          // L1 chunk done     [32]
    int* c1 = flags + 32;     // P2 consumed O1    [32]
    int* px = flags + 64;     // P2 xp slot done   [32]
    int* cx = flags + 96;     // L2 consumed xp    [32]
    int* p2 = flags + 128;    // L2 chunk done     [32]
    if (bid < 32) {
        stage_L1(bid, smem, x, Wih1, Whh1, bih1, bhh1, o1ring, c1 + bid, p1 + bid);
    } else if (bid < 64) {
        const int t = bid - 32;
        stage_P2(t, o1ring, xpring, Wih2, bih2, bhh2, p1 + t, c1 + t, cx + t, px + t);
    } else if (bid < 96) {
        const int t = bid - 64;
        stage_L2(t, smem, xpring, O2, Whh2, px + t, cx + t, p2 + t);
    } else {
        const int t = bid - 96;
        stage_L3(t, smem, O2, Wih3, Whh3, bih3, bhh3, out, p2 + t);
    }
}

__global__ void zero_flags_k(int* flags) {
    if (threadIdx.x < 160)
        __hip_atomic_store(flags + threadIdx.x, 0, __ATOMIC_RELAXED,
                           __HIP_MEMORY_SCOPE_AGENT);
}

extern "C" void kernel_launch(void* const* d_in, const int* in_sizes, int n_in,
                              void* d_out, int out_size, void* d_ws, size_t ws_size,
                              hipStream_t stream) {
    const float* x = (const float*)d_in[0];
    float* out = (float*)d_out;

    char* ws = (char*)d_ws;
    _Float16* o1ring = (_Float16*)ws;                          // 8,388,608 B
    _Float16* xpring = (_Float16*)(ws + (size_t)8388608);      // 33,554,432 B
    _Float16* O2     = (_Float16*)(ws + (size_t)41943040);     // 67,108,864 B
    int* flags       = (int*)(ws + (size_t)109051904);         // 640 B
    (void)ws_size; (void)in_sizes; (void)n_in; (void)out_size;

    zero_flags_k<<<1, 192, 0, stream>>>(flags);
    mega_k<<<128, 512, 8704, stream>>>(
        x,
        (const float*)d_in[1], (const float*)d_in[2], (const float*)d_in[3], (const float*)d_in[4],
        (const float*)d_in[5], (const float*)d_in[6], (const float*)d_in[7], (const float*)d_in[8],
        (const float*)d_in[9], (const float*)d_in[10], (const float*)d_in[11], (const float*)d_in[12],
        o1ring, xpring, O2, out, flags);
}